// Round 1
// baseline (190.281 us; speedup 1.0000x reference)
//
#include <hip/hip_runtime.h>
#include <hip/hip_bf16.h>
#include <math.h>

#define HID 128
#define NRAD 6
#define TABN 4096          // nearest-neighbor table rows 0..TABN (row TABN = 0, x>=1 gate)
#define CUTOFF_INV 0.2f
#define MZ 95
#define PAD 32             // padded-CSR slots per node (one 128B line); overflow -> spill list
#define OVF_CAP 65536
#define FTR 8              // ftab rows computed per block (W3 reuse x8)

typedef unsigned int uint32;

// ---------- K1 (fused): bf16 T1(+b_lin)/T2 + ftab + edge pass (count + padded scatter) ----------
__global__ void build1(const float* __restrict__ emb, const float* __restrict__ W_lin,
                       const float* __restrict__ freq, const float* __restrict__ W_rbf,
                       const float* __restrict__ b_rbf, const float* __restrict__ b_lin,
                       const int* __restrict__ ei, const float* __restrict__ pos,
                       const int* __restrict__ z,
                       __hip_bfloat16* __restrict__ Tb, float* __restrict__ ftab,
                       int* __restrict__ cnt, int* __restrict__ payload,
                       int* __restrict__ ovfcnt, int2* __restrict__ ovfbuf,
                       int MAXZ, int E) {
    __shared__ float sh[FTR * HID];
    int h   = threadIdx.x;
    int bid = blockIdx.x;
    int nT  = 2 * MAXZ;
    int nF  = (TABN + FTR) / FTR;          // 513 blocks cover rows 0..4103 (clamped to TABN)
    if (bid < nT) {
        int zz = bid >> 1, s = bid & 1;
        sh[h] = emb[zz * HID + h];
        __syncthreads();
        const float* W = W_lin + (size_t)s * HID * HID;
        float acc = (s == 0) ? b_lin[h] : 0.f;   // fold bias into T1
#pragma unroll 8
        for (int k = 0; k < HID; ++k) acc = fmaf(sh[k], W[k * HID + h], acc);
        Tb[(size_t)(s * MAXZ + zz) * HID + h] = __float2bfloat16(acc);
    } else if (bid < nT + nF) {
        int t0 = (bid - nT) * FTR;
        // each thread computes silu(pre) for FTR table rows into LDS
        for (int r = 0; r < FTR; ++r) {
            int t = t0 + r;
            float rbf[NRAD];
            if (t == 0) {
#pragma unroll
                for (int k = 0; k < NRAD; ++k) rbf[k] = freq[k];   // lim x->0 env*sin(fx)=f
            } else if (t >= TABN) {
#pragma unroll
                for (int k = 0; k < NRAD; ++k) rbf[k] = 0.f;       // envelope gate x>=1
            } else {
                float x  = (float)t / (float)TABN;
                float x2 = x * x, x5 = x2 * x2 * x;
                float env = 1.f / x + x5 * (-28.f + x * (48.f + x * (-21.f)));
#pragma unroll
                for (int k = 0; k < NRAD; ++k) rbf[k] = env * sinf(freq[k] * x);
            }
            float pre = b_rbf[h];
#pragma unroll
            for (int k = 0; k < NRAD; ++k) pre = fmaf(rbf[k], W_rbf[k * HID + h], pre);
            sh[r * HID + h] = pre / (1.f + __expf(-pre));   // precise silu (once per table row)
        }
        __syncthreads();
        const float* W3 = W_lin + (size_t)2 * HID * HID;
        float acc[FTR];
#pragma unroll
        for (int r = 0; r < FTR; ++r) acc[r] = 0.f;
#pragma unroll 4
        for (int k = 0; k < HID; ++k) {
            float w = W3[k * HID + h];          // one load feeds 8 FMAs
#pragma unroll
            for (int r = 0; r < FTR; ++r) acc[r] = fmaf(sh[r * HID + k], w, acc[r]);
        }
        for (int r = 0; r < FTR; ++r) {
            int t = t0 + r;
            if (t <= TABN) ftab[(size_t)t * HID + h] = acc[r];
        }
    } else {
        // edge pass: distance -> table index, rank via one atomic, direct padded write
        int e = (bid - nT - nF) * HID + h;
        if (e < E) {
            int i = ei[e];
            int j = ei[E + e];
            float dx = pos[3 * i]     - pos[3 * j];
            float dy = pos[3 * i + 1] - pos[3 * j + 1];
            float dz = pos[3 * i + 2] - pos[3 * j + 2];
            float d  = sqrtf(dx * dx + dy * dy + dz * dz);
            float u  = fminf(d * CUTOFF_INV, 1.0f) * (float)TABN;
            int   ti = (int)(u + 0.5f);          // nearest
            if (ti > TABN) ti = TABN;
            int pl = ti | (z[i] << 13) | (z[j] << 20);
            int r  = atomicAdd(&cnt[j], 1);
            if (r < PAD) {
                payload[(size_t)j * PAD + r] = pl;
            } else {
                int o = atomicAdd(ovfcnt, 1);
                if (o < OVF_CAP) ovfbuf[o] = make_int2(j, pl);
            }
        }
    }
}

// per-edge contribution: 4 h-values per lane (h = h4..h4+3), accumulate into ax..aw
#define EDGE_ACC(pl_) do {                                                                    \
    int ti_ = (pl_) & 0x1FFF;                                                                 \
    int zi_ = ((pl_) >> 13) & 0x7F;                                                           \
    int zj_ = ((pl_) >> 20) & 0x7F;                                                           \
    float4 f_ = *(const float4*)(ftab + (size_t)ti_ * HID + h4);                              \
    uint32 a0_ = sT[zi_ * (HID / 2) + l2];                                                    \
    uint32 a1_ = sT[zi_ * (HID / 2) + l2 + 1];                                                \
    uint32 b0_ = sT[(MZ + zj_) * (HID / 2) + l2];                                             \
    uint32 b1_ = sT[(MZ + zj_) * (HID / 2) + l2 + 1];                                         \
    float p0_ = __uint_as_float(a0_ << 16)         + __uint_as_float(b0_ << 16)         + f_.x; \
    float p1_ = __uint_as_float(a0_ & 0xFFFF0000u) + __uint_as_float(b0_ & 0xFFFF0000u) + f_.y; \
    float p2_ = __uint_as_float(a1_ << 16)         + __uint_as_float(b1_ << 16)         + f_.z; \
    float p3_ = __uint_as_float(a1_ & 0xFFFF0000u) + __uint_as_float(b1_ & 0xFFFF0000u) + f_.w; \
    ax = fmaf(p0_, __builtin_amdgcn_rcpf(1.f + __expf(-p0_)), ax);                            \
    ay = fmaf(p1_, __builtin_amdgcn_rcpf(1.f + __expf(-p1_)), ay);                            \
    az = fmaf(p2_, __builtin_amdgcn_rcpf(1.f + __expf(-p2_)), az);                            \
    aw = fmaf(p3_, __builtin_amdgcn_rcpf(1.f + __expf(-p3_)), aw);                            \
} while (0)

// ---------- gather: 2 nodes per wave (half-wave each), float4 per lane, ovf folded in ----------
__launch_bounds__(1024)
__global__ void gather_k(const int* __restrict__ cnt, const int* __restrict__ payload,
                         const uint32* __restrict__ Tb32, const float* __restrict__ ftab,
                         const int* __restrict__ ovfcnt, const int2* __restrict__ ovfbuf,
                         float* __restrict__ out, int N) {
    __shared__ uint32 sT[2 * MZ * (HID / 2)];    // 48640 B, bf16 pairs
    int tid = threadIdx.x;
    for (int k = tid; k < 2 * MZ * (HID / 2); k += 1024) sT[k] = Tb32[k];
    __syncthreads();

    int lane = tid & 63, wv = tid >> 6;          // 16 waves/block, 2 nodes/wave
    int hi   = (lane >> 5) & 1;                  // half index: 0 -> node A, 1 -> node B
    int l32  = lane & 31;
    int h4   = l32 * 4;                          // 4 floats per lane
    int l2   = l32 * 2;                          // uint32-pair index into sT rows
    int nCh  = (N + 31) >> 5;                    // 32 nodes per block
    int nov  = *ovfcnt;
    if (nov > OVF_CAP) nov = OVF_CAP;

    for (int ch = blockIdx.x; ch < nCh; ch += gridDim.x) {
        int nA = (ch << 5) + (wv << 1);
        if (nA >= N) continue;
        int  n      = nA + hi;
        bool nvalid = (n < N);
        int deg = 0, plv = 0;
        if (nvalid) {
            deg = cnt[n];                                    // true degree (may exceed PAD)
            plv = payload[(size_t)n * PAD + l32];            // 256B contiguous per wave
        }
        int cb  = deg < PAD ? deg : PAD;
        int cbA = __builtin_amdgcn_readlane(cb, 0);
        int cbB = __builtin_amdgcn_readlane(cb, 32);
        int cbm = cbA > cbB ? cbA : cbB;

        float ax = 0.f, ay = 0.f, az = 0.f, aw = 0.f;
        for (int k = 0; k < cbm; ++k) {
            int plA = __builtin_amdgcn_readlane(plv, k);      // SGPR broadcast, node A edge k
            int plB = __builtin_amdgcn_readlane(plv, k + 32); // node B edge k
            int pl  = hi ? plB : plA;
            if (k < cb) {                                     // per-half predicate (uniform in half)
                EDGE_ACC(pl);
            }
        }
        // overflow edges (deg > PAD): owning wave folds them in (list empty in practice)
        if (deg > PAD && nov > 0) {
            for (int o = 0; o < nov; ++o) {
                int2 v = ovfbuf[o];
                if (v.x == n) { int pl = v.y; EDGE_ACC(pl); }
            }
        }
        if (nvalid) {
            float s = (deg > 0) ? 1.0f / (float)deg : 0.0f;
            float4 o4;
            o4.x = ax * s; o4.y = ay * s; o4.z = az * s; o4.w = aw * s;
            *(float4*)(out + (size_t)n * HID + h4) = o4;      // 1KB contiguous per wave
        }
    }
}

// ---------- launch ----------
extern "C" void kernel_launch(void* const* d_in, const int* in_sizes, int n_in,
                              void* d_out, int out_size, void* d_ws, size_t ws_size,
                              hipStream_t stream) {
    const int*   z     = (const int*)d_in[0];
    const float* pos   = (const float*)d_in[1];
    const int*   ei    = (const int*)d_in[2];
    const float* freq  = (const float*)d_in[3];
    const float* emb   = (const float*)d_in[4];
    const float* W_rbf = (const float*)d_in[5];
    const float* b_rbf = (const float*)d_in[6];
    const float* W_lin = (const float*)d_in[7];
    const float* b_lin = (const float*)d_in[8];

    int N    = in_sizes[0];
    int E    = in_sizes[2] / 2;
    int MAXZ = in_sizes[4] / HID;   // 95 == MZ
    float* out = (float*)d_out;

    int N_pad = ((N + 1024) / 1024) * 1024;   // multiple of 1024, strictly > N

    char* ws = (char*)d_ws;
    size_t off = 0;
    auto alloc = [&](size_t bytes) { char* p = ws + off; off = (off + bytes + 255) & ~(size_t)255; return p; };
    int*   cnt     = (int*)alloc((size_t)N_pad * 4);     // N_pad*4 is 256-aligned
    int*   ovfcnt  = (int*)alloc(256);                   // adjacent to cnt for one memset
    __hip_bfloat16* Tb = (__hip_bfloat16*)alloc((size_t)2 * MAXZ * HID * 2);
    float* ftab    = (float*)alloc((size_t)(TABN + 1) * HID * 4);
    int*   payload = (int*)alloc((size_t)N_pad * PAD * 4);
    int2*  ovfbuf  = (int2*)alloc((size_t)OVF_CAP * 8);

    hipMemsetAsync(cnt, 0, (size_t)N_pad * 4 + 256, stream);   // zeros cnt + ovfcnt

    int nBuild = 2 * MAXZ + (TABN + FTR) / FTR + (E + HID - 1) / HID;
    build1<<<nBuild, HID, 0, stream>>>(emb, W_lin, freq, W_rbf, b_rbf, b_lin,
                                       ei, pos, z, Tb, ftab, cnt, payload,
                                       ovfcnt, ovfbuf, MAXZ, E);
    gather_k<<<512, 1024, 0, stream>>>(cnt, payload, (const uint32*)Tb, ftab,
                                       ovfcnt, ovfbuf, out, N);
}

// Round 2
// 186.838 us; speedup vs baseline: 1.0184x; 1.0184x over previous
//
#include <hip/hip_runtime.h>
#include <hip/hip_bf16.h>
#include <math.h>

#define HID 128
#define NRAD 6
#define TABN 4096          // nearest-neighbor table rows 0..TABN (row TABN = 0, x>=1 gate)
#define CUTOFF_INV 0.2f
#define MZ 95
#define MZP (MZ + 1)       // +1 sentinel row (index 95, value -60 -> silu contribution == 0)
#define SENT ((MZ << 13) | (MZ << 20))
#define PAD 32             // padded-CSR slots per node (one 128B line); overflow -> spill list
#define OVF_CAP 65536
#define FTR 8              // ftab rows computed per block (W3 reuse x8)

typedef unsigned int uint32;

// ---------- K1 (fused): bf16 T1(+b_lin)/T2 (+sentinel row) + ftab + edge pass ----------
__global__ void build1(const float* __restrict__ emb, const float* __restrict__ W_lin,
                       const float* __restrict__ freq, const float* __restrict__ W_rbf,
                       const float* __restrict__ b_rbf, const float* __restrict__ b_lin,
                       const int* __restrict__ ei, const float* __restrict__ pos,
                       const int* __restrict__ z,
                       __hip_bfloat16* __restrict__ Tb, float* __restrict__ ftab,
                       int* __restrict__ cnt, int* __restrict__ payload,
                       int* __restrict__ ovfcnt, int2* __restrict__ ovfbuf,
                       int MAXZ, int E) {
    __shared__ float sh[FTR * HID];
    int h   = threadIdx.x;
    int bid = blockIdx.x;
    int nT  = 2 * (MAXZ + 1);
    int nF  = (TABN + FTR) / FTR;          // 513 blocks cover rows 0..4103 (clamped to TABN)
    if (bid < nT) {
        int zz = bid >> 1, s = bid & 1;
        if (zz == MAXZ) {                  // sentinel row: -60 => sigmoid==0 => zero contribution
            Tb[(size_t)(s * (MAXZ + 1) + zz) * HID + h] = __float2bfloat16(-60.0f);
            return;
        }
        sh[h] = emb[zz * HID + h];
        __syncthreads();
        const float* W = W_lin + (size_t)s * HID * HID;
        float acc = (s == 0) ? b_lin[h] : 0.f;   // fold bias into T1
#pragma unroll 8
        for (int k = 0; k < HID; ++k) acc = fmaf(sh[k], W[k * HID + h], acc);
        Tb[(size_t)(s * (MAXZ + 1) + zz) * HID + h] = __float2bfloat16(acc);
    } else if (bid < nT + nF) {
        int t0 = (bid - nT) * FTR;
        // each thread computes silu(pre) for FTR table rows into LDS
        for (int r = 0; r < FTR; ++r) {
            int t = t0 + r;
            float rbf[NRAD];
            if (t == 0) {
#pragma unroll
                for (int k = 0; k < NRAD; ++k) rbf[k] = freq[k];   // lim x->0 env*sin(fx)=f
            } else if (t >= TABN) {
#pragma unroll
                for (int k = 0; k < NRAD; ++k) rbf[k] = 0.f;       // envelope gate x>=1
            } else {
                float x  = (float)t / (float)TABN;
                float x2 = x * x, x5 = x2 * x2 * x;
                float env = 1.f / x + x5 * (-28.f + x * (48.f + x * (-21.f)));
#pragma unroll
                for (int k = 0; k < NRAD; ++k) rbf[k] = env * sinf(freq[k] * x);
            }
            float pre = b_rbf[h];
#pragma unroll
            for (int k = 0; k < NRAD; ++k) pre = fmaf(rbf[k], W_rbf[k * HID + h], pre);
            sh[r * HID + h] = pre / (1.f + __expf(-pre));   // precise silu (once per table row)
        }
        __syncthreads();
        const float* W3 = W_lin + (size_t)2 * HID * HID;
        float acc[FTR];
#pragma unroll
        for (int r = 0; r < FTR; ++r) acc[r] = 0.f;
#pragma unroll 4
        for (int k = 0; k < HID; ++k) {
            float w = W3[k * HID + h];          // one load feeds 8 FMAs
#pragma unroll
            for (int r = 0; r < FTR; ++r) acc[r] = fmaf(sh[r * HID + k], w, acc[r]);
        }
        for (int r = 0; r < FTR; ++r) {
            int t = t0 + r;
            if (t <= TABN) ftab[(size_t)t * HID + h] = acc[r];
        }
    } else {
        // edge pass: distance -> table index, rank via one atomic, direct padded write
        int e = (bid - nT - nF) * HID + h;
        if (e < E) {
            int i = ei[e];
            int j = ei[E + e];
            float dx = pos[3 * i]     - pos[3 * j];
            float dy = pos[3 * i + 1] - pos[3 * j + 1];
            float dz = pos[3 * i + 2] - pos[3 * j + 2];
            float d  = sqrtf(dx * dx + dy * dy + dz * dz);
            float u  = fminf(d * CUTOFF_INV, 1.0f) * (float)TABN;
            int   ti = (int)(u + 0.5f);          // nearest
            if (ti > TABN) ti = TABN;
            int pl = ti | (z[i] << 13) | (z[j] << 20);
            int r  = atomicAdd(&cnt[j], 1);
            if (r < PAD) {
                payload[(size_t)j * PAD + r] = pl;
            } else {
                int o = atomicAdd(ovfcnt, 1);
                if (o < OVF_CAP) ovfbuf[o] = make_int2(j, pl);
            }
        }
    }
}

// per-edge contribution: 4 h-values per lane (h = h4..h4+3), accumulate into ax..aw
// branch-free: sentinel payloads contribute exactly 0 (sigmoid underflows to 0)
#define EDGE_ACC(pl_) do {                                                                    \
    int ti_ = (pl_) & 0x1FFF;                                                                 \
    int zi_ = ((pl_) >> 13) & 0x7F;                                                           \
    int zj_ = ((pl_) >> 20) & 0x7F;                                                           \
    float4 f_ = *(const float4*)((const char*)ftab + (uint32)((ti_ << 9) + fb4));             \
    uint32 a0_ = sT[zi_ * (HID / 2) + l2];                                                    \
    uint32 a1_ = sT[zi_ * (HID / 2) + l2 + 1];                                                \
    uint32 b0_ = sT[(MZP + zj_) * (HID / 2) + l2];                                            \
    uint32 b1_ = sT[(MZP + zj_) * (HID / 2) + l2 + 1];                                        \
    float p0_ = __uint_as_float(a0_ << 16)         + __uint_as_float(b0_ << 16)         + f_.x; \
    float p1_ = __uint_as_float(a0_ & 0xFFFF0000u) + __uint_as_float(b0_ & 0xFFFF0000u) + f_.y; \
    float p2_ = __uint_as_float(a1_ << 16)         + __uint_as_float(b1_ << 16)         + f_.z; \
    float p3_ = __uint_as_float(a1_ & 0xFFFF0000u) + __uint_as_float(b1_ & 0xFFFF0000u) + f_.w; \
    ax = fmaf(p0_, __builtin_amdgcn_rcpf(1.f + __expf(-p0_)), ax);                            \
    ay = fmaf(p1_, __builtin_amdgcn_rcpf(1.f + __expf(-p1_)), ay);                            \
    az = fmaf(p2_, __builtin_amdgcn_rcpf(1.f + __expf(-p2_)), az);                            \
    aw = fmaf(p3_, __builtin_amdgcn_rcpf(1.f + __expf(-p3_)), aw);                            \
} while (0)

// ---------- gather: 1 node per wave, 2 edges per iteration (half-wave each), branch-free loop ----------
__launch_bounds__(1024)
__global__ void gather_k(const int* __restrict__ cnt, const int* __restrict__ payload,
                         const uint32* __restrict__ Tb32, const float* __restrict__ ftab,
                         const int* __restrict__ ovfcnt, const int2* __restrict__ ovfbuf,
                         float* __restrict__ out, int N) {
    __shared__ uint32 sT[2 * MZP * (HID / 2)];   // 49152 B, bf16 pairs (incl sentinel rows)
    int tid = threadIdx.x;
    for (int k = tid; k < 2 * MZP * (HID / 2); k += 1024) sT[k] = Tb32[k];
    __syncthreads();

    int lane = tid & 63, wv = tid >> 6;          // 16 waves/block, 1 node/wave
    int hi   = lane >> 5;                        // half index: 0 -> edge 2k, 1 -> edge 2k+1
    int l32  = lane & 31;
    int h4   = l32 * 4;                          // 4 floats per lane (both halves cover h 0..127)
    int l2   = l32 * 2;                          // uint32-pair index into sT rows
    uint32 fb4 = (uint32)h4 << 2;                // byte offset within ftab row
    int nov  = *ovfcnt;
    if (nov > OVF_CAP) nov = OVF_CAP;
    int nW = gridDim.x << 4;                     // total waves

    for (int n = (blockIdx.x << 4) + wv; n < N; n += nW) {
        int deg = cnt[n];                                    // true degree (may exceed PAD)
        int plv = payload[(size_t)n * PAD + l32];            // 128B line, both halves mirror it
        int cb  = deg < PAD ? deg : PAD;
        plv = (l32 < cb) ? plv : SENT;                       // in-register sentinel pad
        int nit = (cb + 1) >> 1;

        float ax = 0.f, ay = 0.f, az = 0.f, aw = 0.f;
        for (int k = 0; k < nit; ++k) {
            int plA = __builtin_amdgcn_readlane(plv, 2 * k);      // SGPR broadcast, edge 2k
            int plB = __builtin_amdgcn_readlane(plv, 2 * k + 1);  // edge 2k+1 (or sentinel)
            int pl  = hi ? plB : plA;
            EDGE_ACC(pl);
        }
        // overflow edges (deg > PAD): owning wave folds them in (list empty in practice)
        if (deg > PAD && nov > 0) {
            for (int o = 0; o < nov; ++o) {
                int2 v = ovfbuf[o];
                if (v.x == n) { int pl = v.y; EDGE_ACC(pl); }
            }
        }
        // merge the two half-wave accumulators (same h range)
        ax += __shfl_xor(ax, 32);
        ay += __shfl_xor(ay, 32);
        az += __shfl_xor(az, 32);
        aw += __shfl_xor(aw, 32);
        if (hi == 0) {
            float s = (deg > 0) ? 1.0f / (float)deg : 0.0f;
            float4 o4;
            o4.x = ax * s; o4.y = ay * s; o4.z = az * s; o4.w = aw * s;
            *(float4*)(out + (size_t)n * HID + h4) = o4;     // 512B contiguous row per wave
        }
    }
}

// ---------- launch ----------
extern "C" void kernel_launch(void* const* d_in, const int* in_sizes, int n_in,
                              void* d_out, int out_size, void* d_ws, size_t ws_size,
                              hipStream_t stream) {
    const int*   z     = (const int*)d_in[0];
    const float* pos   = (const float*)d_in[1];
    const int*   ei    = (const int*)d_in[2];
    const float* freq  = (const float*)d_in[3];
    const float* emb   = (const float*)d_in[4];
    const float* W_rbf = (const float*)d_in[5];
    const float* b_rbf = (const float*)d_in[6];
    const float* W_lin = (const float*)d_in[7];
    const float* b_lin = (const float*)d_in[8];

    int N    = in_sizes[0];
    int E    = in_sizes[2] / 2;
    int MAXZ = in_sizes[4] / HID;   // 95 == MZ
    float* out = (float*)d_out;

    int N_pad = ((N + 1024) / 1024) * 1024;   // multiple of 1024, strictly > N

    char* ws = (char*)d_ws;
    size_t off = 0;
    auto alloc = [&](size_t bytes) { char* p = ws + off; off = (off + bytes + 255) & ~(size_t)255; return p; };
    int*   cnt     = (int*)alloc((size_t)N_pad * 4);     // N_pad*4 is 256-aligned
    int*   ovfcnt  = (int*)alloc(256);                   // adjacent to cnt for one memset
    __hip_bfloat16* Tb = (__hip_bfloat16*)alloc((size_t)2 * (MAXZ + 1) * HID * 2);
    float* ftab    = (float*)alloc((size_t)(TABN + 1) * HID * 4);
    int*   payload = (int*)alloc((size_t)N_pad * PAD * 4);
    int2*  ovfbuf  = (int2*)alloc((size_t)OVF_CAP * 8);

    hipMemsetAsync(cnt, 0, (size_t)N_pad * 4 + 256, stream);   // zeros cnt + ovfcnt

    int nBuild = 2 * (MAXZ + 1) + (TABN + FTR) / FTR + (E + HID - 1) / HID;
    build1<<<nBuild, HID, 0, stream>>>(emb, W_lin, freq, W_rbf, b_rbf, b_lin,
                                       ei, pos, z, Tb, ftab, cnt, payload,
                                       ovfcnt, ovfbuf, MAXZ, E);
    gather_k<<<512, 1024, 0, stream>>>(cnt, payload, (const uint32*)Tb, ftab,
                                       ovfcnt, ovfbuf, out, N);
}